// Round 3
// baseline (712.184 us; speedup 1.0000x reference)
//
#include <hip/hip_runtime.h>
#include <math.h>

// Problem constants (fixed by the reference)
#define BB 4
#define QQ 300
#define CC 256          // QUERY_DIM
#define NH 8
#define HD 32           // head dim
#define HWN 10000       // H*W
#define ROWLEN (NH * HWN)   // 80000
#define NTILE 20        // hw tiles of 512 (256 threads x 2)
#define NSLOT (NH * NTILE * 4)  // 640 partial slots per (b,q)
#define NORM_FACT 0.17677669529663687f  // 32^-0.5

// ---------------------------------------------------------------------------
// P0: kwT[c][o] = kw[o][c]  (256x256, one-shot, ~2us)
// ---------------------------------------------------------------------------
__global__ void transpose_kw_kernel(const float* __restrict__ kw,
                                    float* __restrict__ kwT) {
    const int c = blockIdx.x;
    const int o = threadIdx.x;
    kwT[c * CC + o] = kw[o * CC + c];
}

// ---------------------------------------------------------------------------
// P1: qp[b,q,h] = NORM_FACT * (sum_c q[b,q,c]*q_w[h,c] + q_b[h])
// ---------------------------------------------------------------------------
__global__ void qproj_kernel(const float* __restrict__ q,
                             const float* __restrict__ qw,
                             const float* __restrict__ qb,
                             float* __restrict__ qp) {
    __shared__ float qrow[CC];
    const int bq = blockIdx.x;
    const int h  = threadIdx.x;
    qrow[h] = q[bq * CC + h];
    __syncthreads();
    float acc = qb[h];
    const float* wr = qw + h * CC;
    #pragma unroll 4
    for (int c = 0; c < CC; c += 4) {
        float4 w = *reinterpret_cast<const float4*>(wr + c);
        float4 x = *reinterpret_cast<const float4*>(&qrow[c]);
        acc += w.x * x.x + w.y * x.y + w.z * x.z + w.w * x.w;
    }
    qp[bq * CC + h] = acc * NORM_FACT;
}

// ---------------------------------------------------------------------------
// P2: kp[b,o,hw] = sum_c k_w[o,c]*k[b,c,hw] + k_b[o]
// OTILE=64 outputs/block, 2 hw/thread; kwT rows are wave-uniform -> s_load.
// ---------------------------------------------------------------------------
__global__ __launch_bounds__(256, 2)
void kproj_kernel(const float* __restrict__ k,
                  const float* __restrict__ kwT,
                  const float* __restrict__ kb,
                  float* __restrict__ kp) {
    const int hwt = blockIdx.x, ot = blockIdx.y, b = blockIdx.z;
    const int hw = hwt * 512 + threadIdx.x * 2;
    const bool valid = hw < HWN;

    float2 acc[64];
    #pragma unroll
    for (int o = 0; o < 64; ++o) {
        const float bv = kb[ot * 64 + o];   // uniform -> SGPR
        acc[o].x = bv; acc[o].y = bv;
    }

    const float* kbase = k + (size_t)b * CC * HWN + hw;
    for (int c = 0; c < CC; ++c) {
        const float2 kv = valid ? *reinterpret_cast<const float2*>(kbase + (size_t)c * HWN)
                                : make_float2(0.f, 0.f);
        const float* wrow = kwT + c * CC + ot * 64;   // uniform row -> s_load
        #pragma unroll
        for (int o = 0; o < 64; ++o) {
            acc[o].x += wrow[o] * kv.x;
            acc[o].y += wrow[o] * kv.y;
        }
    }

    if (valid) {
        float* kpp = kp + ((size_t)b * CC + ot * 64) * HWN + hw;
        #pragma unroll
        for (int o = 0; o < 64; ++o)
            *reinterpret_cast<float2*>(kpp + (size_t)o * HWN) = acc[o];
    }
}

// ---------------------------------------------------------------------------
// P3: softmax denominator partials. Each thread owns 2 hw points (kp column
// in 64 VGPRs); q-side rows are wave-uniform -> scalar loads. No LDS.
// ---------------------------------------------------------------------------
__global__ __launch_bounds__(256, 4)
void attn_stats_kernel(const float* __restrict__ qp,
                       const float* __restrict__ kp,
                       const int* __restrict__ mask,
                       float* __restrict__ partials) {
    const int hwt = blockIdx.x, n = blockIdx.y, b = blockIdx.z;
    const int hw = hwt * 512 + threadIdx.x * 2;
    const bool valid = hw < HWN;

    float2 kc[HD];
    const float* kpp = kp + ((size_t)b * CC + n * HD) * HWN + hw;
    #pragma unroll
    for (int d = 0; d < HD; ++d)
        kc[d] = valid ? *reinterpret_cast<const float2*>(kpp + (size_t)d * HWN)
                      : make_float2(0.f, 0.f);

    float mx = 0.f, my = 0.f;
    if (valid) {
        const int2 mv = *reinterpret_cast<const int2*>(mask + b * HWN + hw);
        mx = mv.x ? 0.f : 1.f;
        my = mv.y ? 0.f : 1.f;
    }

    const int lane = threadIdx.x & 63;
    const int slot = (n * NTILE + hwt) * 4 + (threadIdx.x >> 6);
    float* prow = partials + slot;
    const float* qbase = qp + (size_t)b * QQ * CC + n * HD;

    for (int qq = 0; qq < QQ; ++qq) {
        const float* qrow = qbase + (size_t)qq * CC;   // uniform -> s_load
        float ax = 0.f, ay = 0.f;
        #pragma unroll
        for (int d = 0; d < HD; ++d) {
            const float qv = qrow[d];
            ax += qv * kc[d].x;
            ay += qv * kc[d].y;
        }
        float e = __expf(ax) * mx + __expf(ay) * my;
        #pragma unroll
        for (int m = 1; m < 64; m <<= 1) e += __shfl_xor(e, m, 64);
        if (lane == 0) prow[(size_t)(b * QQ + qq) * NSLOT] = e;
    }
}

// ---------------------------------------------------------------------------
// P4: invS[row] = 1 / sum(partials[row][0..640))
// ---------------------------------------------------------------------------
__global__ void invsum_kernel(const float* __restrict__ partials,
                              float* __restrict__ invS) {
    __shared__ float sl[4];
    const int row = blockIdx.x;
    const int tid = threadIdx.x;
    float s = 0.f;
    for (int i = tid; i < NSLOT; i += 256) s += partials[(size_t)row * NSLOT + i];
    #pragma unroll
    for (int m = 1; m < 64; m <<= 1) s += __shfl_xor(s, m, 64);
    if ((tid & 63) == 0) sl[tid >> 6] = s;
    __syncthreads();
    if (tid == 0) invS[row] = 1.0f / (sl[0] + sl[1] + sl[2] + sl[3]);
}

// ---------------------------------------------------------------------------
// P5: out = masked ? 0 : exp(logit) * invS   (recompute logits, float2 stores)
// ---------------------------------------------------------------------------
__global__ __launch_bounds__(256, 4)
void attn_out_kernel(const float* __restrict__ qp,
                     const float* __restrict__ kp,
                     const int* __restrict__ mask,
                     const float* __restrict__ invS,
                     float* __restrict__ out) {
    const int hwt = blockIdx.x, n = blockIdx.y, b = blockIdx.z;
    const int hw = hwt * 512 + threadIdx.x * 2;
    if (hw >= HWN) return;   // no cross-lane ops here: safe to exit

    float2 kc[HD];
    const float* kpp = kp + ((size_t)b * CC + n * HD) * HWN + hw;
    #pragma unroll
    for (int d = 0; d < HD; ++d)
        kc[d] = *reinterpret_cast<const float2*>(kpp + (size_t)d * HWN);

    const int2 mv = *reinterpret_cast<const int2*>(mask + b * HWN + hw);
    const float mx = mv.x ? 0.f : 1.f;
    const float my = mv.y ? 0.f : 1.f;

    const float* qbase = qp + (size_t)b * QQ * CC + n * HD;
    float* outp = out + (size_t)b * QQ * ROWLEN + (size_t)n * HWN + hw;

    for (int qq = 0; qq < QQ; ++qq) {
        const float* qrow = qbase + (size_t)qq * CC;   // uniform -> s_load
        float ax = 0.f, ay = 0.f;
        #pragma unroll
        for (int d = 0; d < HD; ++d) {
            const float qv = qrow[d];
            ax += qv * kc[d].x;
            ay += qv * kc[d].y;
        }
        const float is = invS[b * QQ + qq];            // uniform -> s_load
        float2 r;
        r.x = __expf(ax) * is * mx;
        r.y = __expf(ay) * is * my;
        *reinterpret_cast<float2*>(outp + (size_t)qq * ROWLEN) = r;
    }
}

// ---------------------------------------------------------------------------
extern "C" void kernel_launch(void* const* d_in, const int* in_sizes, int n_in,
                              void* d_out, int out_size, void* d_ws, size_t ws_size,
                              hipStream_t stream) {
    const float* q    = (const float*)d_in[0];
    const float* k    = (const float*)d_in[1];
    const int*   mask = (const int*)d_in[2];
    const float* qw   = (const float*)d_in[3];
    const float* qb   = (const float*)d_in[4];
    const float* kw   = (const float*)d_in[5];
    const float* kb   = (const float*)d_in[6];
    float* out = (float*)d_out;                  // [4,300,8,100,100] = 96M floats

    float* ws = (float*)d_ws;
    float* qp   = ws;                            // 307,200 f32
    float* kp   = ws + 307200;                   // 10,240,000 f32
    float* invS = ws + 307200 + 10240000;        // 1,200 f32
    // Temporaries inside d_out (stream-ordered; fully overwritten by P5):
    float* kwT      = out;                       // 65,536 f32
    float* partials = out + (1 << 20);           // 768,000 f32

    transpose_kw_kernel<<<CC, CC, 0, stream>>>(kw, kwT);
    qproj_kernel<<<BB * QQ, 256, 0, stream>>>(q, qw, qb, qp);
    kproj_kernel<<<dim3(NTILE, 4, BB), 256, 0, stream>>>(k, kwT, kb, kp);
    attn_stats_kernel<<<dim3(NTILE, NH, BB), 256, 0, stream>>>(qp, kp, mask, partials);
    invsum_kernel<<<BB * QQ, 256, 0, stream>>>(partials, invS);
    attn_out_kernel<<<dim3(NTILE, NH, BB), 256, 0, stream>>>(qp, kp, mask, invS, out);
}

// Round 4
// 558.929 us; speedup vs baseline: 1.2742x; 1.2742x over previous
//
#include <hip/hip_runtime.h>
#include <math.h>

// Problem constants (fixed by the reference)
#define BB 4
#define QQ 300
#define CC 256          // QUERY_DIM
#define NH 8
#define HD 32           // head dim
#define HWN 10000       // H*W
#define ROWLEN (NH * HWN)   // 80000
#define CHUNK 100       // hw per stats block
#define NCH (HWN / CHUNK)   // 100
#define NSLOT (NH * NCH)    // 800 partial slots per (b,q)
#define QT 75           // q per attn_out block (4 tiles)
#define NORM_FACT 0.17677669529663687f  // 32^-0.5

// ---------------------------------------------------------------------------
// P0: kwT[c][o] = kw[o][c]
// ---------------------------------------------------------------------------
__global__ void transpose_kw_kernel(const float* __restrict__ kw,
                                    float* __restrict__ kwT) {
    const int c = blockIdx.x;
    const int o = threadIdx.x;
    kwT[c * CC + o] = kw[o * CC + c];
}

// ---------------------------------------------------------------------------
// P1: qp[b,q,h] = NORM_FACT * (sum_c q[b,q,c]*q_w[h,c] + q_b[h])
// ---------------------------------------------------------------------------
__global__ void qproj_kernel(const float* __restrict__ q,
                             const float* __restrict__ qw,
                             const float* __restrict__ qb,
                             float* __restrict__ qp) {
    __shared__ float qrow[CC];
    const int bq = blockIdx.x;
    const int h  = threadIdx.x;
    qrow[h] = q[bq * CC + h];
    __syncthreads();
    float acc = qb[h];
    const float* wr = qw + h * CC;
    #pragma unroll 4
    for (int c = 0; c < CC; c += 4) {
        float4 w = *reinterpret_cast<const float4*>(wr + c);
        float4 x = *reinterpret_cast<const float4*>(&qrow[c]);
        acc += w.x * x.x + w.y * x.y + w.z * x.z + w.w * x.w;
    }
    qp[bq * CC + h] = acc * NORM_FACT;
}

// ---------------------------------------------------------------------------
// P2: kp[b,o,hw] (o-major) AND kp_t[b,hw,o] (hw-major) = k_w @ k + k_b
// thread owns one hw; acc[64] scalar f32; kwT rows wave-uniform -> s_load.
// ---------------------------------------------------------------------------
__global__ __launch_bounds__(256, 2)
void kproj_kernel(const float* __restrict__ k,
                  const float* __restrict__ kwT,
                  const float* __restrict__ kb,
                  float* __restrict__ kp,
                  float* __restrict__ kp_t) {
    const int hwt = blockIdx.x, ot = blockIdx.y, b = blockIdx.z;
    const int hw = hwt * 256 + threadIdx.x;
    const bool valid = hw < HWN;

    float acc[64];
    const float* bptr = kb + ot * 64;            // uniform -> s_load
    #pragma unroll
    for (int o = 0; o < 64; ++o) acc[o] = bptr[o];

    const float* kbase = k + (size_t)b * CC * HWN + (valid ? hw : 0);
    const float* wbase = kwT + ot * 64;
    #pragma unroll 4
    for (int c = 0; c < CC; ++c) {
        const float kv = kbase[(size_t)c * HWN];
        const float* wr = wbase + c * CC;        // uniform row -> s_load
        #pragma unroll
        for (int o = 0; o < 64; ++o) acc[o] += wr[o] * kv;
    }

    if (valid) {
        float* p1 = kp + ((size_t)(b * CC + ot * 64)) * HWN + hw;
        #pragma unroll
        for (int o = 0; o < 64; ++o) p1[(size_t)o * HWN] = acc[o];
        float* p2 = kp_t + ((size_t)(b * HWN + hw)) * CC + ot * 64;
        #pragma unroll
        for (int o = 0; o < 64; o += 4)
            *reinterpret_cast<float4*>(p2 + o) =
                make_float4(acc[o], acc[o + 1], acc[o + 2], acc[o + 3]);
    }
}

// ---------------------------------------------------------------------------
// P3: softmax denominator partials — LANE OWNS Q. kp_t column + mask are
// wave-uniform (s_load); denominator accumulates in a register. No shuffles.
// grid (100, 8, 4) x 320 threads (5 waves; lanes 300..319 idle on store).
// ---------------------------------------------------------------------------
__global__ __launch_bounds__(320, 4)
void attn_stats_kernel(const float* __restrict__ qp,
                       const float* __restrict__ kp_t,
                       const int* __restrict__ mask,
                       float* __restrict__ partials) {
    const int ch = blockIdx.x, n = blockIdx.y, b = blockIdx.z;
    const int t = threadIdx.x;                   // = q index
    const bool qv = t < QQ;

    float qrow[HD];
    const float* qptr = qp + ((size_t)(b * QQ + (qv ? t : 0))) * CC + n * HD;
    #pragma unroll
    for (int d = 0; d < HD; d += 4) {
        const float4 v = *reinterpret_cast<const float4*>(qptr + d);
        qrow[d] = v.x; qrow[d + 1] = v.y; qrow[d + 2] = v.z; qrow[d + 3] = v.w;
    }

    float denom = 0.f;
    const int hw0 = ch * CHUNK;
    const float* colbase = kp_t + ((size_t)(b * HWN + hw0)) * CC + n * HD;
    const int* mbase = mask + b * HWN + hw0;

    #pragma unroll 2
    for (int i = 0; i < CHUNK; ++i) {
        const float* col = colbase + (size_t)i * CC;   // uniform -> s_load
        const float mfac = (mbase[i] == 0) ? 1.f : 0.f; // uniform
        float a0 = 0.f, a1 = 0.f, a2 = 0.f, a3 = 0.f;
        #pragma unroll
        for (int d = 0; d < HD; d += 4) {
            a0 += col[d]     * qrow[d];
            a1 += col[d + 1] * qrow[d + 1];
            a2 += col[d + 2] * qrow[d + 2];
            a3 += col[d + 3] * qrow[d + 3];
        }
        denom += __expf((a0 + a1) + (a2 + a3)) * mfac;
    }

    if (qv) partials[((size_t)(b * QQ + t) * NH + n) * NCH + ch] = denom;
}

// ---------------------------------------------------------------------------
// P4: invS[row] = 1 / sum(partials[row][0..800))
// ---------------------------------------------------------------------------
__global__ void invsum_kernel(const float* __restrict__ partials,
                              float* __restrict__ invS) {
    __shared__ float sl[4];
    const int row = blockIdx.x;
    const int tid = threadIdx.x;
    float s = 0.f;
    for (int i = tid; i < NSLOT; i += 256) s += partials[(size_t)row * NSLOT + i];
    #pragma unroll
    for (int m = 1; m < 64; m <<= 1) s += __shfl_xor(s, m, 64);
    if ((tid & 63) == 0) sl[tid >> 6] = s;
    __syncthreads();
    if (tid == 0) invS[row] = 1.0f / (sl[0] + sl[1] + sl[2] + sl[3]);
}

// ---------------------------------------------------------------------------
// P5: out = masked ? 0 : exp(logit)*invS — LANE OWNS HW (coalesced stores),
// q split 4x across blocks for occupancy. grid (20, 32, 4) x 256.
// ---------------------------------------------------------------------------
__global__ __launch_bounds__(256, 2)
void attn_out_kernel(const float* __restrict__ qp,
                     const float* __restrict__ kp,
                     const int* __restrict__ mask,
                     const float* __restrict__ invS,
                     float* __restrict__ out) {
    const int hwt = blockIdx.x;
    const int n = blockIdx.y & 7, qt = blockIdx.y >> 3;
    const int b = blockIdx.z;
    const int hw = hwt * 512 + threadIdx.x * 2;
    if (hw >= HWN) return;

    float2 kc[HD];
    const float* kpp = kp + ((size_t)(b * CC + n * HD)) * HWN + hw;
    #pragma unroll
    for (int d = 0; d < HD; ++d)
        kc[d] = *reinterpret_cast<const float2*>(kpp + (size_t)d * HWN);

    const int2 mv = *reinterpret_cast<const int2*>(mask + b * HWN + hw);
    const float mx = mv.x ? 0.f : 1.f;
    const float my = mv.y ? 0.f : 1.f;

    const int q0 = qt * QT;
    const float* qbase = qp + ((size_t)(b * QQ + q0)) * CC + n * HD;
    const float* isbase = invS + b * QQ + q0;
    float* outp = out + ((size_t)(b * QQ + q0) * NH + n) * HWN + hw;

    #pragma unroll 2
    for (int qq = 0; qq < QT; ++qq) {
        const float* qrow = qbase + (size_t)qq * CC;   // uniform -> s_load
        float ax0 = 0.f, ax1 = 0.f, ay0 = 0.f, ay1 = 0.f;
        #pragma unroll
        for (int d = 0; d < HD; d += 2) {
            const float q0v = qrow[d], q1v = qrow[d + 1];
            ax0 += q0v * kc[d].x;     ay0 += q0v * kc[d].y;
            ax1 += q1v * kc[d + 1].x; ay1 += q1v * kc[d + 1].y;
        }
        const float is = isbase[qq];                   // uniform -> s_load
        float2 r;
        r.x = __expf(ax0 + ax1) * is * mx;
        r.y = __expf(ay0 + ay1) * is * my;
        *reinterpret_cast<float2*>(outp + (size_t)qq * ROWLEN) = r;
    }
}

// ---------------------------------------------------------------------------
extern "C" void kernel_launch(void* const* d_in, const int* in_sizes, int n_in,
                              void* d_out, int out_size, void* d_ws, size_t ws_size,
                              hipStream_t stream) {
    const float* q    = (const float*)d_in[0];
    const float* k    = (const float*)d_in[1];
    const int*   mask = (const int*)d_in[2];
    const float* qw   = (const float*)d_in[3];
    const float* qb   = (const float*)d_in[4];
    const float* kw   = (const float*)d_in[5];
    const float* kb   = (const float*)d_in[6];
    float* out = (float*)d_out;                  // 96,000,000 floats

    // ws: proven footprint (42 MB)
    float* ws = (float*)d_ws;
    float* qp   = ws;                            // 307,200
    float* kp   = ws + 307200;                   // 10,240,000 (o-major)
    float* invS = ws + 307200 + 10240000;        // 1,200

    // scratch parked in d_out (stream-ordered; P5 overwrites everything):
    float* kwT      = out;                       // 65,536
    float* kp_t     = out + (1 << 20);           // 10,240,000 (hw-major)
    float* partials = out + (12 << 20);          // 960,000

    transpose_kw_kernel<<<CC, CC, 0, stream>>>(kw, kwT);
    qproj_kernel<<<BB * QQ, 256, 0, stream>>>(q, qw, qb, qp);
    kproj_kernel<<<dim3(40, 4, BB), 256, 0, stream>>>(k, kwT, kb, kp, kp_t);
    attn_stats_kernel<<<dim3(NCH, NH, BB), 320, 0, stream>>>(qp, kp_t, mask, partials);
    invsum_kernel<<<BB * QQ, 256, 0, stream>>>(partials, invS);
    attn_out_kernel<<<dim3(20, 32, BB), 256, 0, stream>>>(qp, kp, mask, invS, out);
}

// Round 5
// 315.267 us; speedup vs baseline: 2.2590x; 1.7729x over previous
//
#include <hip/hip_runtime.h>
#include <math.h>

// Problem constants (fixed by the reference)
#define BB 4
#define QQ 300
#define CC 256          // QUERY_DIM / hidden
#define NH 8
#define HD 32           // head dim
#define HWN 10000       // H*W
#define MT 19           // q tiles of 16 (300 -> 304 via row clamp)
#define NT 625          // hw tiles of 16
#define NCHUNK 25       // N-tile chunks per (b,n,mt)
#define TPC 25          // tiles per chunk (25*25=625)
#define NORM_FACT 0.17677669529663687f  // 32^-0.5

typedef __attribute__((ext_vector_type(8))) short short8_t;   // 8 bf16 (4 VGPR)
typedef __attribute__((ext_vector_type(4))) float f32x4_t;    // MFMA C/D

union FragU { uint32_t u[4]; short8_t v; };

__device__ __forceinline__ unsigned short bf16_rn(float x) {
    uint32_t u = __float_as_uint(x);
    return (unsigned short)((u + 0x7fffu + ((u >> 16) & 1u)) >> 16);
}
__device__ __forceinline__ float bf16_f(unsigned short h) {
    return __uint_as_float(((uint32_t)h) << 16);
}

// ---------------------------------------------------------------------------
// P0: pre-pack kw (split bf16) into kproj's exact B-fragment order.
// B[k=c][col=o] for tile (ot,ks): lane l, j -> kw[ot*16+(l&15)][ks*32+(l>>4)*8+j]
// ---------------------------------------------------------------------------
__global__ void prep_kwB_kernel(const float* __restrict__ kw,
                                unsigned short* __restrict__ kwB_hi,
                                unsigned short* __restrict__ kwB_lo) {
    const int ot = blockIdx.x, ks = blockIdx.y;    // 16 x 8
    const int l = threadIdx.x;                     // 64
    const int o = ot * 16 + (l & 15);
    const int c0 = ks * 32 + (l >> 4) * 8;
    const size_t base = ((size_t)(ot * 8 + ks) * 64 + l) * 8;
    #pragma unroll
    for (int j = 0; j < 8; ++j) {
        const float x = kw[o * CC + c0 + j];
        const unsigned short h = bf16_rn(x);
        kwB_hi[base + j] = h;
        kwB_lo[base + j] = bf16_rn(x - bf16_f(h));
    }
}

// ---------------------------------------------------------------------------
// P1: qp = NORM_FACT*(q @ qw^T + qb), written as split-bf16 planes [b][q][256]
// ---------------------------------------------------------------------------
__global__ void qproj_kernel(const float* __restrict__ q,
                             const float* __restrict__ qw,
                             const float* __restrict__ qb,
                             unsigned short* __restrict__ qp_hi,
                             unsigned short* __restrict__ qp_lo) {
    __shared__ float qrow[CC];
    const int bq = blockIdx.x;          // b*300 + qi
    const int h  = threadIdx.x;
    qrow[h] = q[bq * CC + h];
    __syncthreads();
    float acc = qb[h];
    const float* wr = qw + h * CC;
    #pragma unroll 4
    for (int c = 0; c < CC; c += 4) {
        float4 w = *reinterpret_cast<const float4*>(wr + c);
        float4 x = *reinterpret_cast<const float4*>(&qrow[c]);
        acc += w.x * x.x + w.y * x.y + w.z * x.z + w.w * x.w;
    }
    acc *= NORM_FACT;
    const unsigned short hi = bf16_rn(acc);
    qp_hi[bq * CC + h] = hi;
    qp_lo[bq * CC + h] = bf16_rn(acc - bf16_f(hi));
}

// ---------------------------------------------------------------------------
// P2: kproj via MFMA. Per wave: one (b, hw-tile of 16 rows); C[hw][o] =
// k^T @ kw^T + kb, K=256 (8 ksteps), 16 o-tiles; split-bf16 (3 MFMA/step).
// Output: kp planes bf16, hw-major [b][hw][256].
// ---------------------------------------------------------------------------
__global__ __launch_bounds__(256)
void kproj_kernel(const float* __restrict__ kin,
                  const unsigned short* __restrict__ kwB_hi,
                  const unsigned short* __restrict__ kwB_lo,
                  const float* __restrict__ kb,
                  unsigned short* __restrict__ kp_hi,
                  unsigned short* __restrict__ kp_lo) {
    const int wid = threadIdx.x >> 6, l = threadIdx.x & 63;
    const int wu = blockIdx.x * 4 + wid;          // 0..2499
    const int hwt = wu % NT;
    const int b   = wu / NT;
    const int hw  = hwt * 16 + (l & 15);          // A row
    const int jb  = (l >> 4) * 8;                 // k sub-base

    // A-frags: k input (f32) -> split bf16, 8 ksteps
    FragU a_hi[8], a_lo[8];
    const float* kbase = kin + (size_t)b * CC * HWN + hw;
    #pragma unroll
    for (int ks = 0; ks < 8; ++ks) {
        #pragma unroll
        for (int t = 0; t < 4; ++t) {
            const int c = ks * 32 + jb + 2 * t;
            const float x0 = kbase[(size_t)c * HWN];
            const float x1 = kbase[(size_t)(c + 1) * HWN];
            const unsigned short h0 = bf16_rn(x0), h1 = bf16_rn(x1);
            const unsigned short q0 = bf16_rn(x0 - bf16_f(h0));
            const unsigned short q1 = bf16_rn(x1 - bf16_f(h1));
            a_hi[ks].u[t] = (uint32_t)h0 | ((uint32_t)h1 << 16);
            a_lo[ks].u[t] = (uint32_t)q0 | ((uint32_t)q1 << 16);
        }
    }

    #pragma unroll 1
    for (int ot = 0; ot < 16; ++ot) {
        const float bias = kb[ot * 16 + (l & 15)];
        f32x4_t c = {bias, bias, bias, bias};
        #pragma unroll
        for (int ks = 0; ks < 8; ++ks) {
            const size_t fb = ((size_t)(ot * 8 + ks) * 64 + l) * 8;
            const short8_t bh = *reinterpret_cast<const short8_t*>(kwB_hi + fb);
            const short8_t bl = *reinterpret_cast<const short8_t*>(kwB_lo + fb);
            c = __builtin_amdgcn_mfma_f32_16x16x32_bf16(a_hi[ks].v, bh, c, 0, 0, 0);
            c = __builtin_amdgcn_mfma_f32_16x16x32_bf16(a_hi[ks].v, bl, c, 0, 0, 0);
            c = __builtin_amdgcn_mfma_f32_16x16x32_bf16(a_lo[ks].v, bh, c, 0, 0, 0);
        }
        // C: row(hw) = (l>>4)*4+r, col(o) = ot*16+(l&15)
        #pragma unroll
        for (int r = 0; r < 4; ++r) {
            const int hwrow = hwt * 16 + (l >> 4) * 4 + r;
            const size_t idx = ((size_t)b * HWN + hwrow) * CC + ot * 16 + (l & 15);
            const unsigned short h = bf16_rn(c[r]);
            kp_hi[idx] = h;
            kp_lo[idx] = bf16_rn(c[r] - bf16_f(h));
        }
    }
}

// ---------------------------------------------------------------------------
// Shared wave-unit decode for the attention passes:
// wu -> (b, n, mt, ch); wave computes 16q x (25 tiles of 16 hw).
// ---------------------------------------------------------------------------
__global__ __launch_bounds__(256)
void attn_stats_kernel(const unsigned short* __restrict__ qp_hi,
                       const unsigned short* __restrict__ qp_lo,
                       const unsigned short* __restrict__ kp_hi,
                       const unsigned short* __restrict__ kp_lo,
                       const int* __restrict__ mask,
                       float* __restrict__ partials) {
    const int wid = threadIdx.x >> 6, l = threadIdx.x & 63;
    const int wu = blockIdx.x * 4 + wid;          // 15200
    const int ch = wu % NCHUNK;
    int tmp = wu / NCHUNK;
    const int mt = tmp % MT; tmp /= MT;
    const int n = tmp & 7;
    const int b = tmp >> 3;

    const int qa = mt * 16 + (l & 15);
    const int qc = qa < QQ ? qa : QQ - 1;         // clamp pad rows
    const size_t abase = ((size_t)(b * QQ + qc)) * CC + n * HD + (l >> 4) * 8;
    const short8_t ah = *reinterpret_cast<const short8_t*>(qp_hi + abase);
    const short8_t al = *reinterpret_cast<const short8_t*>(qp_lo + abase);

    float acc0 = 0.f, acc1 = 0.f, acc2 = 0.f, acc3 = 0.f;
    const int hwc = l & 15;
    #pragma unroll 2
    for (int t = 0; t < TPC; ++t) {
        const int hw = (ch * TPC + t) * 16 + hwc;
        const size_t bbase = ((size_t)(b * HWN + hw)) * CC + n * HD + (l >> 4) * 8;
        const short8_t bh = *reinterpret_cast<const short8_t*>(kp_hi + bbase);
        const short8_t bl = *reinterpret_cast<const short8_t*>(kp_lo + bbase);
        const float mfac = mask[b * HWN + hw] ? 0.f : 1.f;
        f32x4_t c = {0.f, 0.f, 0.f, 0.f};
        c = __builtin_amdgcn_mfma_f32_16x16x32_bf16(ah, bh, c, 0, 0, 0);
        c = __builtin_amdgcn_mfma_f32_16x16x32_bf16(ah, bl, c, 0, 0, 0);
        c = __builtin_amdgcn_mfma_f32_16x16x32_bf16(al, bh, c, 0, 0, 0);
        acc0 += __expf(c[0]) * mfac;
        acc1 += __expf(c[1]) * mfac;
        acc2 += __expf(c[2]) * mfac;
        acc3 += __expf(c[3]) * mfac;
    }
    #pragma unroll
    for (int m = 1; m < 16; m <<= 1) {
        acc0 += __shfl_xor(acc0, m, 64);
        acc1 += __shfl_xor(acc1, m, 64);
        acc2 += __shfl_xor(acc2, m, 64);
        acc3 += __shfl_xor(acc3, m, 64);
    }
    if ((l & 15) == 0) {
        const int rbase = mt * 16 + (l >> 4) * 4;
        const float a[4] = {acc0, acc1, acc2, acc3};
        #pragma unroll
        for (int r = 0; r < 4; ++r) {
            const int qr = rbase + r;
            if (qr < QQ)
                partials[(((size_t)b * QQ + qr) * NH + n) * NCHUNK + ch] = a[r];
        }
    }
}

// ---------------------------------------------------------------------------
// P4: invS[b,q] = 1 / sum over (n,ch) of partials  (200 values per row)
// ---------------------------------------------------------------------------
__global__ void invsum_kernel(const float* __restrict__ partials,
                              float* __restrict__ invS) {
    const int row = blockIdx.x;    // 1200
    const int l = threadIdx.x;     // 64
    float s = 0.f;
    const float* p = partials + (size_t)row * (NH * NCHUNK);
    for (int i = l; i < NH * NCHUNK; i += 64) s += p[i];
    #pragma unroll
    for (int m = 1; m < 64; m <<= 1) s += __shfl_xor(s, m, 64);
    if (l == 0) invS[row] = 1.0f / s;
}

// ---------------------------------------------------------------------------
// P5: out = exp(logit) * invS * mfac   (recompute via MFMA, nontemporal store)
// ---------------------------------------------------------------------------
__global__ __launch_bounds__(256)
void attn_out_kernel(const unsigned short* __restrict__ qp_hi,
                     const unsigned short* __restrict__ qp_lo,
                     const unsigned short* __restrict__ kp_hi,
                     const unsigned short* __restrict__ kp_lo,
                     const int* __restrict__ mask,
                     const float* __restrict__ invS,
                     float* __restrict__ out) {
    const int wid = threadIdx.x >> 6, l = threadIdx.x & 63;
    const int wu = blockIdx.x * 4 + wid;
    const int ch = wu % NCHUNK;
    int tmp = wu / NCHUNK;
    const int mt = tmp % MT; tmp /= MT;
    const int n = tmp & 7;
    const int b = tmp >> 3;

    const int qa = mt * 16 + (l & 15);
    const int qc = qa < QQ ? qa : QQ - 1;
    const size_t abase = ((size_t)(b * QQ + qc)) * CC + n * HD + (l >> 4) * 8;
    const short8_t ah = *reinterpret_cast<const short8_t*>(qp_hi + abase);
    const short8_t al = *reinterpret_cast<const short8_t*>(qp_lo + abase);

    const int rbase = mt * 16 + (l >> 4) * 4;     // C-row q base for this lane
    const int q0 = rbase + 0 < QQ ? rbase + 0 : QQ - 1;
    const int q1 = rbase + 1 < QQ ? rbase + 1 : QQ - 1;
    const int q2 = rbase + 2 < QQ ? rbase + 2 : QQ - 1;
    const int q3 = rbase + 3 < QQ ? rbase + 3 : QQ - 1;
    const float is0 = invS[b * QQ + q0];
    const float is1 = invS[b * QQ + q1];
    const float is2 = invS[b * QQ + q2];
    const float is3 = invS[b * QQ + q3];
    float* const o0 = out + (((size_t)b * QQ + q0) * NH + n) * HWN;
    float* const o1 = out + (((size_t)b * QQ + q1) * NH + n) * HWN;
    float* const o2 = out + (((size_t)b * QQ + q2) * NH + n) * HWN;
    float* const o3 = out + (((size_t)b * QQ + q3) * NH + n) * HWN;
    const bool s0 = rbase + 0 < QQ, s1 = rbase + 1 < QQ,
               s2 = rbase + 2 < QQ, s3 = rbase + 3 < QQ;

    const int hwc = l & 15;
    #pragma unroll 2
    for (int t = 0; t < TPC; ++t) {
        const int hw = (ch * TPC + t) * 16 + hwc;
        const size_t bbase = ((size_t)(b * HWN + hw)) * CC + n * HD + (l >> 4) * 8;
        const short8_t bh = *reinterpret_cast<const short8_t*>(kp_hi + bbase);
        const short8_t bl = *reinterpret_cast<const short8_t*>(kp_lo + bbase);
        const float mfac = mask[b * HWN + hw] ? 0.f : 1.f;
        f32x4_t c = {0.f, 0.f, 0.f, 0.f};
        c = __builtin_amdgcn_mfma_f32_16x16x32_bf16(ah, bh, c, 0, 0, 0);
        c = __builtin_amdgcn_mfma_f32_16x16x32_bf16(ah, bl, c, 0, 0, 0);
        c = __builtin_amdgcn_mfma_f32_16x16x32_bf16(al, bh, c, 0, 0, 0);
        if (s0) __builtin_nontemporal_store(__expf(c[0]) * is0 * mfac, o0 + hw);
        if (s1) __builtin_nontemporal_store(__expf(c[1]) * is1 * mfac, o1 + hw);
        if (s2) __builtin_nontemporal_store(__expf(c[2]) * is2 * mfac, o2 + hw);
        if (s3) __builtin_nontemporal_store(__expf(c[3]) * is3 * mfac, o3 + hw);
    }
}

// ---------------------------------------------------------------------------
extern "C" void kernel_launch(void* const* d_in, const int* in_sizes, int n_in,
                              void* d_out, int out_size, void* d_ws, size_t ws_size,
                              hipStream_t stream) {
    const float* q    = (const float*)d_in[0];
    const float* k    = (const float*)d_in[1];
    const int*   mask = (const int*)d_in[2];
    const float* qw   = (const float*)d_in[3];
    const float* qb   = (const float*)d_in[4];
    const float* kw   = (const float*)d_in[5];
    const float* kb   = (const float*)d_in[6];
    float* out = (float*)d_out;

    // ws layout (bytes) — total 42,193,600 B, identical to the proven footprint:
    //   [0, 20.48M)   kp_hi  ushort[4*10000*256]
    //   [20.48M, 40.96M) kp_lo
    //   [40.96M, +614400) qp_hi ushort[4*300*256]
    //   [.., +614400)     qp_lo
    //   [.., +4800)       invS  float[1200]
    char* wsb = (char*)d_ws;
    unsigned short* kp_hi = (unsigned short*)wsb;
    unsigned short* kp_lo = (unsigned short*)(wsb + 20480000);
    unsigned short* qp_hi = (unsigned short*)(wsb + 40960000);
    unsigned short* qp_lo = (unsigned short*)(wsb + 40960000 + 614400);
    float* invS           = (float*)(wsb + 40960000 + 1228800);

    // scratch parked in d_out (stream-ordered; P5 overwrites all of d_out):
    //   kwB planes at byte 0 (2*128KB), partials at byte 2MB (960KB)
    unsigned short* kwB_hi = (unsigned short*)d_out;
    unsigned short* kwB_lo = kwB_hi + 65536;
    float* partials = (float*)((char*)d_out + (2u << 20));

    prep_kwB_kernel<<<dim3(16, 8), 64, 0, stream>>>(kw, kwB_hi, kwB_lo);
    qproj_kernel<<<BB * QQ, 256, 0, stream>>>(q, qw, qb, qp_hi, qp_lo);
    kproj_kernel<<<(BB * NT) / 4, 256, 0, stream>>>(k, kwB_hi, kwB_lo, kb, kp_hi, kp_lo);
    attn_stats_kernel<<<(BB * NH * MT * NCHUNK) / 4, 256, 0, stream>>>(
        qp_hi, qp_lo, kp_hi, kp_lo, mask, partials);
    invsum_kernel<<<BB * QQ, 64, 0, stream>>>(partials, invS);
    attn_out_kernel<<<(BB * NH * MT * NCHUNK) / 4, 256, 0, stream>>>(
        qp_hi, qp_lo, kp_hi, kp_lo, mask, invS, out);
}

// Round 6
// 307.494 us; speedup vs baseline: 2.3161x; 1.0253x over previous
//
#include <hip/hip_runtime.h>
#include <math.h>

// Problem constants (fixed by the reference)
#define BB 4
#define QQ 300
#define CC 256          // QUERY_DIM / hidden
#define NH 8
#define HD 32           // head dim
#define HWN 10000       // H*W
#define MT 19           // q tiles of 16 (300 -> 304 via row clamp)
#define NT 625          // hw tiles of 16
#define NCHUNK 25       // N-tile chunks per (b,n,mt)
#define TPC 25          // tiles per chunk (25*25=625)
#define NORM_FACT 0.17677669529663687f  // 32^-0.5

typedef __attribute__((ext_vector_type(8))) short short8_t;   // 8 bf16 (4 VGPR)
typedef __attribute__((ext_vector_type(4))) float f32x4_t;    // MFMA C/D

union FragU { uint32_t u[4]; short8_t v; };

__device__ __forceinline__ unsigned short bf16_rn(float x) {
    uint32_t u = __float_as_uint(x);
    return (unsigned short)((u + 0x7fffu + ((u >> 16) & 1u)) >> 16);
}
__device__ __forceinline__ float bf16_f(unsigned short h) {
    return __uint_as_float(((uint32_t)h) << 16);
}

// ---------------------------------------------------------------------------
// P0: pre-pack kw (split bf16) into kproj's exact B-fragment order.
// B[k=c][col=o] for tile (ot,ks): lane l, j -> kw[ot*16+(l&15)][ks*32+(l>>4)*8+j]
// ---------------------------------------------------------------------------
__global__ void prep_kwB_kernel(const float* __restrict__ kw,
                                unsigned short* __restrict__ kwB_hi,
                                unsigned short* __restrict__ kwB_lo) {
    const int ot = blockIdx.x, ks = blockIdx.y;    // 16 x 8
    const int l = threadIdx.x;                     // 64
    const int o = ot * 16 + (l & 15);
    const int c0 = ks * 32 + (l >> 4) * 8;
    const size_t base = ((size_t)(ot * 8 + ks) * 64 + l) * 8;
    #pragma unroll
    for (int j = 0; j < 8; ++j) {
        const float x = kw[o * CC + c0 + j];
        const unsigned short h = bf16_rn(x);
        kwB_hi[base + j] = h;
        kwB_lo[base + j] = bf16_rn(x - bf16_f(h));
    }
}

// ---------------------------------------------------------------------------
// P1: qp = NORM_FACT*(q @ qw^T + qb) -> interleaved split-bf16
// qp_il[((b*QQ+q)*NH + n)*64 + {0..31 hi, 32..63 lo}]
// ---------------------------------------------------------------------------
__global__ void qproj_kernel(const float* __restrict__ q,
                             const float* __restrict__ qw,
                             const float* __restrict__ qb,
                             unsigned short* __restrict__ qp_il) {
    __shared__ float qrow[CC];
    const int bq = blockIdx.x;          // b*300 + qi
    const int h  = threadIdx.x;
    qrow[h] = q[bq * CC + h];
    __syncthreads();
    float acc = qb[h];
    const float* wr = qw + h * CC;
    #pragma unroll 4
    for (int c = 0; c < CC; c += 4) {
        float4 w = *reinterpret_cast<const float4*>(wr + c);
        float4 x = *reinterpret_cast<const float4*>(&qrow[c]);
        acc += w.x * x.x + w.y * x.y + w.z * x.z + w.w * x.w;
    }
    acc *= NORM_FACT;
    const unsigned short hi = bf16_rn(acc);
    const size_t base = ((size_t)bq * NH + (h >> 5)) * 64 + (h & 31);
    qp_il[base]      = hi;
    qp_il[base + 32] = bf16_rn(acc - bf16_f(hi));
}

// ---------------------------------------------------------------------------
// P2 v2: kproj via MFMA, occupancy-fixed. Wave = (b, hw-tile16, o-quarter64).
// 10000 waves (~9.8/SIMD). A-frags streamed per k-step (8 VGPR live), C =
// 4 x f32x4. k re-read 4x but L3-resident (41 MB). Split-bf16: 3 MFMA/step.
// Output: kp_il[((b*HWN+hw)*NH + n)*64 + {hi 0..31, lo 32..63}]
// ---------------------------------------------------------------------------
__global__ __launch_bounds__(256)
void kproj_kernel(const float* __restrict__ kin,
                  const unsigned short* __restrict__ kwB_hi,
                  const unsigned short* __restrict__ kwB_lo,
                  const float* __restrict__ kb,
                  unsigned short* __restrict__ kp_il) {
    const int wid = threadIdx.x >> 6, l = threadIdx.x & 63;
    const int wu  = blockIdx.x * 4 + wid;         // 0..9999
    const int ot4 = wu & 3;                       // o-quarter (4 ot-tiles)
    const int rem = wu >> 2;
    const int hwt = rem % NT;
    const int b   = rem / NT;
    const int hw  = hwt * 16 + (l & 15);          // A row
    const int jb  = (l >> 4) * 8;                 // k sub-base

    f32x4_t acc[4];
    #pragma unroll
    for (int t = 0; t < 4; ++t) {
        const float bias = kb[(ot4 * 4 + t) * 16 + (l & 15)];
        acc[t] = {bias, bias, bias, bias};
    }

    const float* kbase = kin + (size_t)b * CC * HWN + hw;
    #pragma unroll 2
    for (int ks = 0; ks < 8; ++ks) {
        FragU a_hi, a_lo;
        #pragma unroll
        for (int tt = 0; tt < 4; ++tt) {
            const int c = ks * 32 + jb + 2 * tt;
            const float x0 = kbase[(size_t)c * HWN];
            const float x1 = kbase[(size_t)(c + 1) * HWN];
            const unsigned short h0 = bf16_rn(x0), h1 = bf16_rn(x1);
            const unsigned short g0 = bf16_rn(x0 - bf16_f(h0));
            const unsigned short g1 = bf16_rn(x1 - bf16_f(h1));
            a_hi.u[tt] = (uint32_t)h0 | ((uint32_t)h1 << 16);
            a_lo.u[tt] = (uint32_t)g0 | ((uint32_t)g1 << 16);
        }
        #pragma unroll
        for (int t = 0; t < 4; ++t) {
            const int ot = ot4 * 4 + t;
            const size_t fb = ((size_t)(ot * 8 + ks) * 64 + l) * 8;
            const short8_t bh = *reinterpret_cast<const short8_t*>(kwB_hi + fb);
            const short8_t bl = *reinterpret_cast<const short8_t*>(kwB_lo + fb);
            acc[t] = __builtin_amdgcn_mfma_f32_16x16x32_bf16(a_hi.v, bh, acc[t], 0, 0, 0);
            acc[t] = __builtin_amdgcn_mfma_f32_16x16x32_bf16(a_hi.v, bl, acc[t], 0, 0, 0);
            acc[t] = __builtin_amdgcn_mfma_f32_16x16x32_bf16(a_lo.v, bh, acc[t], 0, 0, 0);
        }
    }

    // C: row(hw) = (l>>4)*4+r, col(o) = ot*16+(l&15); store interleaved planes
    #pragma unroll
    for (int t = 0; t < 4; ++t) {
        const int o = (ot4 * 4 + t) * 16 + (l & 15);
        const int n = o >> 5, osub = o & 31;
        #pragma unroll
        for (int r = 0; r < 4; ++r) {
            const int hwrow = hwt * 16 + (l >> 4) * 4 + r;
            const size_t base = ((size_t)(b * HWN + hwrow) * NH + n) * 64 + osub;
            const float v = acc[t][r];
            const unsigned short h = bf16_rn(v);
            kp_il[base]      = h;
            kp_il[base + 32] = bf16_rn(v - bf16_f(h));
        }
    }
}

// ---------------------------------------------------------------------------
// P3: softmax denominator partials via MFMA.
// wu -> (b, n, mt, ch); wave computes 16q x (25 tiles of 16 hw).
// ---------------------------------------------------------------------------
__global__ __launch_bounds__(256)
void attn_stats_kernel(const unsigned short* __restrict__ qp_il,
                       const unsigned short* __restrict__ kp_il,
                       const int* __restrict__ mask,
                       float* __restrict__ partials) {
    const int wid = threadIdx.x >> 6, l = threadIdx.x & 63;
    const int wu = blockIdx.x * 4 + wid;          // 15200
    const int ch = wu % NCHUNK;
    int tmp = wu / NCHUNK;
    const int mt = tmp % MT; tmp /= MT;
    const int n = tmp & 7;
    const int b = tmp >> 3;

    const int qa = mt * 16 + (l & 15);
    const int qc = qa < QQ ? qa : QQ - 1;         // clamp pad rows
    const size_t abase = ((size_t)(b * QQ + qc) * NH + n) * 64 + (l >> 4) * 8;
    const short8_t ah = *reinterpret_cast<const short8_t*>(qp_il + abase);
    const short8_t al = *reinterpret_cast<const short8_t*>(qp_il + abase + 32);

    float acc0 = 0.f, acc1 = 0.f, acc2 = 0.f, acc3 = 0.f;
    const int hwc = l & 15;
    #pragma unroll 2
    for (int t = 0; t < TPC; ++t) {
        const int hw = (ch * TPC + t) * 16 + hwc;
        const size_t bbase = ((size_t)(b * HWN + hw) * NH + n) * 64 + (l >> 4) * 8;
        const short8_t bh = *reinterpret_cast<const short8_t*>(kp_il + bbase);
        const short8_t bl = *reinterpret_cast<const short8_t*>(kp_il + bbase + 32);
        const float mfac = mask[b * HWN + hw] ? 0.f : 1.f;
        f32x4_t c = {0.f, 0.f, 0.f, 0.f};
        c = __builtin_amdgcn_mfma_f32_16x16x32_bf16(ah, bh, c, 0, 0, 0);
        c = __builtin_amdgcn_mfma_f32_16x16x32_bf16(ah, bl, c, 0, 0, 0);
        c = __builtin_amdgcn_mfma_f32_16x16x32_bf16(al, bh, c, 0, 0, 0);
        acc0 += __expf(c[0]) * mfac;
        acc1 += __expf(c[1]) * mfac;
        acc2 += __expf(c[2]) * mfac;
        acc3 += __expf(c[3]) * mfac;
    }
    #pragma unroll
    for (int m = 1; m < 16; m <<= 1) {
        acc0 += __shfl_xor(acc0, m, 64);
        acc1 += __shfl_xor(acc1, m, 64);
        acc2 += __shfl_xor(acc2, m, 64);
        acc3 += __shfl_xor(acc3, m, 64);
    }
    if ((l & 15) == 0) {
        const int rbase = mt * 16 + (l >> 4) * 4;
        const float a[4] = {acc0, acc1, acc2, acc3};
        #pragma unroll
        for (int r = 0; r < 4; ++r) {
            const int qr = rbase + r;
            if (qr < QQ)
                partials[(((size_t)b * QQ + qr) * NH + n) * NCHUNK + ch] = a[r];
        }
    }
}

// ---------------------------------------------------------------------------
// P4: invS[b,q] = 1 / sum over (n,ch) of partials  (200 values per row)
// ---------------------------------------------------------------------------
__global__ void invsum_kernel(const float* __restrict__ partials,
                              float* __restrict__ invS) {
    const int row = blockIdx.x;    // 1200
    const int l = threadIdx.x;     // 64
    float s = 0.f;
    const float* p = partials + (size_t)row * (NH * NCHUNK);
    for (int i = l; i < NH * NCHUNK; i += 64) s += p[i];
    #pragma unroll
    for (int m = 1; m < 64; m <<= 1) s += __shfl_xor(s, m, 64);
    if (l == 0) invS[row] = 1.0f / s;
}

// ---------------------------------------------------------------------------
// P5: out = exp(logit) * invS * mfac   (recompute via MFMA, nontemporal store)
// ---------------------------------------------------------------------------
__global__ __launch_bounds__(256)
void attn_out_kernel(const unsigned short* __restrict__ qp_il,
                     const unsigned short* __restrict__ kp_il,
                     const int* __restrict__ mask,
                     const float* __restrict__ invS,
                     float* __restrict__ out) {
    const int wid = threadIdx.x >> 6, l = threadIdx.x & 63;
    const int wu = blockIdx.x * 4 + wid;
    const int ch = wu % NCHUNK;
    int tmp = wu / NCHUNK;
    const int mt = tmp % MT; tmp /= MT;
    const int n = tmp & 7;
    const int b = tmp >> 3;

    const int qa = mt * 16 + (l & 15);
    const int qc = qa < QQ ? qa : QQ - 1;
    const size_t abase = ((size_t)(b * QQ + qc) * NH + n) * 64 + (l >> 4) * 8;
    const short8_t ah = *reinterpret_cast<const short8_t*>(qp_il + abase);
    const short8_t al = *reinterpret_cast<const short8_t*>(qp_il + abase + 32);

    const int rbase = mt * 16 + (l >> 4) * 4;     // C-row q base for this lane
    const int q0 = rbase + 0 < QQ ? rbase + 0 : QQ - 1;
    const int q1 = rbase + 1 < QQ ? rbase + 1 : QQ - 1;
    const int q2 = rbase + 2 < QQ ? rbase + 2 : QQ - 1;
    const int q3 = rbase + 3 < QQ ? rbase + 3 : QQ - 1;
    const float is0 = invS[b * QQ + q0];
    const float is1 = invS[b * QQ + q1];
    const float is2 = invS[b * QQ + q2];
    const float is3 = invS[b * QQ + q3];
    float* const o0 = out + (((size_t)b * QQ + q0) * NH + n) * HWN;
    float* const o1 = out + (((size_t)b * QQ + q1) * NH + n) * HWN;
    float* const o2 = out + (((size_t)b * QQ + q2) * NH + n) * HWN;
    float* const o3 = out + (((size_t)b * QQ + q3) * NH + n) * HWN;
    const bool s0 = rbase + 0 < QQ, s1 = rbase + 1 < QQ,
               s2 = rbase + 2 < QQ, s3 = rbase + 3 < QQ;

    const int hwc = l & 15;
    #pragma unroll 2
    for (int t = 0; t < TPC; ++t) {
        const int hw = (ch * TPC + t) * 16 + hwc;
        const size_t bbase = ((size_t)(b * HWN + hw) * NH + n) * 64 + (l >> 4) * 8;
        const short8_t bh = *reinterpret_cast<const short8_t*>(kp_il + bbase);
        const short8_t bl = *reinterpret_cast<const short8_t*>(kp_il + bbase + 32);
        const float mfac = mask[b * HWN + hw] ? 0.f : 1.f;
        f32x4_t c = {0.f, 0.f, 0.f, 0.f};
        c = __builtin_amdgcn_mfma_f32_16x16x32_bf16(ah, bh, c, 0, 0, 0);
        c = __builtin_amdgcn_mfma_f32_16x16x32_bf16(ah, bl, c, 0, 0, 0);
        c = __builtin_amdgcn_mfma_f32_16x16x32_bf16(al, bh, c, 0, 0, 0);
        if (s0) __builtin_nontemporal_store(__expf(c[0]) * is0 * mfac, o0 + hw);
        if (s1) __builtin_nontemporal_store(__expf(c[1]) * is1 * mfac, o1 + hw);
        if (s2) __builtin_nontemporal_store(__expf(c[2]) * is2 * mfac, o2 + hw);
        if (s3) __builtin_nontemporal_store(__expf(c[3]) * is3 * mfac, o3 + hw);
    }
}

// ---------------------------------------------------------------------------
extern "C" void kernel_launch(void* const* d_in, const int* in_sizes, int n_in,
                              void* d_out, int out_size, void* d_ws, size_t ws_size,
                              hipStream_t stream) {
    const float* q    = (const float*)d_in[0];
    const float* k    = (const float*)d_in[1];
    const int*   mask = (const int*)d_in[2];
    const float* qw   = (const float*)d_in[3];
    const float* qb   = (const float*)d_in[4];
    const float* kw   = (const float*)d_in[5];
    const float* kb   = (const float*)d_in[6];
    float* out = (float*)d_out;

    // ws layout (bytes) — total 42,193,600 B (proven footprint):
    //   [0, 40.96M)          kp_il  ushort[4*10000*8*64]  (hi/lo interleaved)
    //   [40.96M, +1228800)   qp_il  ushort[4*300*8*64]
    //   [.., +4800)          invS   float[1200]
    char* wsb = (char*)d_ws;
    unsigned short* kp_il = (unsigned short*)wsb;
    unsigned short* qp_il = (unsigned short*)(wsb + 40960000);
    float* invS           = (float*)(wsb + 40960000 + 1228800);

    // scratch parked in d_out (stream-ordered; P5 overwrites all of d_out):
    //   kwB planes at byte 0 (2*128KB), partials at byte 2MB (960KB)
    unsigned short* kwB_hi = (unsigned short*)d_out;
    unsigned short* kwB_lo = kwB_hi + 65536;
    float* partials = (float*)((char*)d_out + (2u << 20));

    prep_kwB_kernel<<<dim3(16, 8), 64, 0, stream>>>(kw, kwB_hi, kwB_lo);
    qproj_kernel<<<BB * QQ, 256, 0, stream>>>(q, qw, qb, qp_il);
    kproj_kernel<<<(BB * NT * 4) / 4, 256, 0, stream>>>(k, kwB_hi, kwB_lo, kb, kp_il);
    attn_stats_kernel<<<(BB * NH * MT * NCHUNK) / 4, 256, 0, stream>>>(
        qp_il, kp_il, mask, partials);
    invsum_kernel<<<BB * QQ, 64, 0, stream>>>(partials, invS);
    attn_out_kernel<<<(BB * NH * MT * NCHUNK) / 4, 256, 0, stream>>>(
        qp_il, kp_il, mask, invS, out);
}